// Round 3
// baseline (477.428 us; speedup 1.0000x reference)
//
#include <hip/hip_runtime.h>
#include <hip/hip_bf16.h>
#include <stdint.h>

// B=2, H=16, S=2048, D=64, dropout p=0.1, key = jax.random.key(42)
// JAX >= 0.4.30: threefry_partitionable default ON:
//   bits(f) = y0 ^ y1 where (y0,y1) = threefry2x32(key, (hi=0, lo=f)), f = flat index
typedef __attribute__((ext_vector_type(8))) short short8;
typedef __attribute__((ext_vector_type(4))) float f32x4;
typedef __attribute__((ext_vector_type(2))) float f32x2;
typedef __attribute__((ext_vector_type(4))) uint32_t u32x4;

#define KEEP_TH 0xE6666600u  // bits < TH  <=>  jax uniform(bits) < float32(0.9)

__device__ __forceinline__ uint32_t pack2bf(float a, float b) {
  uint16_t lo = __builtin_bit_cast(uint16_t, __float2bfloat16(a));
  uint16_t hi = __builtin_bit_cast(uint16_t, __float2bfloat16(b));
  return (uint32_t)lo | ((uint32_t)hi << 16);
}

// threefry2x32, key (0,42): ks = [0, 42, 0^42^0x1BD11BDA]; returns y0^y1
__device__ __forceinline__ uint32_t threefry_xor_0_42(uint32_t x0, uint32_t x1) {
  const uint32_t K1 = 42u;
  const uint32_t K2 = 0x1BD11BF0u;
  x1 += K1;                      // x0 += ks[0] (=0) elided
#define TFR(r) { x0 += x1; x1 = (x1 << (r)) | (x1 >> (32 - (r))); x1 ^= x0; }
  TFR(13) TFR(15) TFR(26) TFR(6)
  x0 += K1;  x1 += K2 + 1u;
  TFR(17) TFR(29) TFR(16) TFR(24)
  x0 += K2;  x1 += 2u;
  TFR(13) TFR(15) TFR(26) TFR(6)
             x1 += K1 + 3u;
  TFR(17) TFR(29) TFR(16) TFR(24)
  x0 += K1;  x1 += K2 + 4u;
  TFR(13) TFR(15) TFR(26) TFR(6)
  x0 += K2;  x1 += 5u;
#undef TFR
  return x0 ^ x1;
}

__global__ __launch_bounds__(256, 2)
void attn_dropout_kernel(const float* __restrict__ Qg, const float* __restrict__ Kg,
                         const float* __restrict__ Vg, const float* __restrict__ invs,
                         float* __restrict__ Out) {
  __shared__ __align__(16) uint32_t Kb[2][32][36];   // [batch][key][d-pair]
  __shared__ __align__(16) uint32_t Vt[2][64][36];   // [batch][d][key-pair, XOR-swizzled]
  __shared__ __align__(16) uint32_t Pl[2][4][16][20];// [batch][wave][query e][key-pair]

  const int tid = threadIdx.x;
  const int w = tid >> 6;
  const int l = tid & 63;
  const int e = l & 15;
  const int g = l >> 4;

  const int n  = blockIdx.x;       // 0..511
  const int h  = n & 15;
  const int qc = n >> 4;
  const int qbase = qc * 64;

  const float c = 1.4426950408889634f / invs[0];   // log2(e)/inv_scale (post-MFMA)
  const int sq = qbase + w * 16 + e;               // this lane's query row

  // Q fragments (B operand: col = lane&15 = query, k = d = 8*g + j)
  short8 qf[2][2];
#pragma unroll
  for (int b = 0; b < 2; ++b)
#pragma unroll
    for (int kc = 0; kc < 2; ++kc) {
      const float* qp = Qg + (((b * 2048 + sq) * 16 + h) * 64 + kc * 32 + 8 * g);
      f32x4 q0 = *(const f32x4*)qp;
      f32x4 q1 = *(const f32x4*)(qp + 4);
      u32x4 u;
      u.x = pack2bf(q0.x, q0.y);
      u.y = pack2bf(q0.z, q0.w);
      u.z = pack2bf(q1.x, q1.y);
      u.w = pack2bf(q1.z, q1.w);
      qf[b][kc] = __builtin_bit_cast(short8, u);
    }

  f32x4 acc[2][4];
#pragma unroll
  for (int b = 0; b < 2; ++b)
#pragma unroll
    for (int dt = 0; dt < 4; ++dt) acc[b][dt] = (f32x4){0.f, 0.f, 0.f, 0.f};
  float lsum[2] = {0.f, 0.f};

  // mask flat index: f = b*2^26 + h*2^22 + s*2^11 + t
  const uint32_t jb = ((uint32_t)h << 22) | ((uint32_t)sq << 11);

  // staging roles
  const int k_c  = tid & 31;
  const int k_tr = tid >> 5;
  const int v_d  = tid & 63;
  const int v_tq = tid >> 6;
  const int v_x  = (v_d >> 3) & 3;

  for (int tile = 0; tile < 64; ++tile) {
    const int t0 = tile * 32;
    __syncthreads();
    // stage K
#pragma unroll
    for (int b = 0; b < 2; ++b)
#pragma unroll
      for (int r = 0; r < 4; ++r) {
        int t = k_tr + 8 * r;
        const float* p = Kg + (((b * 2048 + t0 + t) * 16 + h) * 64 + 2 * k_c);
        f32x2 v = *(const f32x2*)p;
        Kb[b][t][k_c] = pack2bf(v.x, v.y);
      }
    // stage V transposed (pair index XOR-swizzled by (d>>3)&3)
#pragma unroll
    for (int b = 0; b < 2; ++b)
#pragma unroll
      for (int r = 0; r < 4; ++r) {
        int t = 2 * (v_tq * 4 + r);
        const float* p = Vg + (((b * 2048 + t0 + t) * 16 + h) * 64 + v_d);
        float va = p[0], vb = p[1024];
        Vt[b][v_d][(t >> 1) ^ (v_x << 2)] = pack2bf(va, vb);
      }
    __syncthreads();

    // QK + softmax numerator + dropout (partitionable threefry, per batch)
#pragma unroll
    for (int b = 0; b < 2; ++b) {
      const uint32_t fb = jb + (b ? 0x04000000u : 0u);
#pragma unroll
      for (int T = 0; T < 2; ++T) {
        u32x4 ku0 = *(const u32x4*)&Kb[b][T * 16 + e][4 * g];
        u32x4 ku1 = *(const u32x4*)&Kb[b][T * 16 + e][16 + 4 * g];
        f32x4 sacc = (f32x4){0.f, 0.f, 0.f, 0.f};
        sacc = __builtin_amdgcn_mfma_f32_16x16x32_bf16(__builtin_bit_cast(short8, ku0), qf[b][0], sacc, 0, 0, 0);
        sacc = __builtin_amdgcn_mfma_f32_16x16x32_bf16(__builtin_bit_cast(short8, ku1), qf[b][1], sacc, 0, 0, 0);
        float pm[4];
#pragma unroll
        for (int r = 0; r < 4; ++r) {
          uint32_t f = fb + (uint32_t)(t0 + T * 16 + 4 * g + r);
          uint32_t bits = threefry_xor_0_42(0u, f);
          float p = exp2f(sacc[r] * c);
          lsum[b] += p;                      // denominator is pre-dropout
          pm[r] = (bits < KEEP_TH) ? p : 0.f;
        }
        Pl[b][w][e][8 * T + 2 * g]     = pack2bf(pm[0], pm[1]);
        Pl[b][w][e][8 * T + 2 * g + 1] = pack2bf(pm[2], pm[3]);
      }
    }

    __syncthreads();   // P relay visibility

    // PV
#pragma unroll
    for (int b = 0; b < 2; ++b) {
      u32x4 pu = *(const u32x4*)&Pl[b][w][e][4 * g];
      short8 pf = __builtin_bit_cast(short8, pu);
#pragma unroll
      for (int dt = 0; dt < 4; ++dt) {
        int d = dt * 16 + e;
        int x = (d >> 3) & 3;
        u32x4 vu = *(const u32x4*)&Vt[b][d][4 * (g ^ x)];
        acc[b][dt] = __builtin_amdgcn_mfma_f32_16x16x32_bf16(pf, __builtin_bit_cast(short8, vu), acc[b][dt], 0, 0, 0);
      }
    }
  }

  // epilogue: out = acc / (0.9 * L)
#pragma unroll
  for (int b = 0; b < 2; ++b) {
    float L = lsum[b];
    L += __shfl_xor(L, 16);
    L += __shfl_xor(L, 32);
    float rinv = 1.0f / (0.9f * L);
    float rr[4];
#pragma unroll
    for (int r = 0; r < 4; ++r) rr[r] = __shfl(rinv, 4 * g + r);
#pragma unroll
    for (int dt = 0; dt < 4; ++dt)
#pragma unroll
      for (int r = 0; r < 4; ++r) {
        int s = qbase + w * 16 + 4 * g + r;
        Out[(((b * 16 + h) * 2048 + s) * 64) + dt * 16 + e] = acc[b][dt][r] * rr[r];
      }
  }
}

extern "C" void kernel_launch(void* const* d_in, const int* in_sizes, int n_in,
                              void* d_out, int out_size, void* d_ws, size_t ws_size,
                              hipStream_t stream) {
  const float* q  = (const float*)d_in[0];
  const float* k  = (const float*)d_in[1];
  const float* v  = (const float*)d_in[2];
  const float* sc = (const float*)d_in[3];
  float* out = (float*)d_out;
  (void)d_ws; (void)ws_size; (void)in_sizes; (void)n_in; (void)out_size;
  attn_dropout_kernel<<<dim3(512), dim3(256), 0, stream>>>(q, k, v, sc, out);
}

// Round 4
// 302.175 us; speedup vs baseline: 1.5800x; 1.5800x over previous
//
#include <hip/hip_runtime.h>
#include <hip/hip_bf16.h>
#include <stdint.h>

// B=2, H=16, S=2048, D=64, dropout p=0.1, key = jax.random.key(42)
// JAX partitionable threefry: bits(f) = y0^y1, (y0,y1)=threefry2x32(key,(0,f))
typedef __attribute__((ext_vector_type(8))) short short8;
typedef __attribute__((ext_vector_type(4))) float f32x4;
typedef __attribute__((ext_vector_type(4))) uint32_t u32x4;
typedef __attribute__((ext_vector_type(2))) uint32_t u32x2;

#define KEEP_TH 0xE6666600u  // bits < TH  <=>  jax uniform(bits) < float32(0.9)

__device__ __forceinline__ uint32_t pack2bf(float a, float b) {
  uint16_t lo = __builtin_bit_cast(uint16_t, __float2bfloat16(a));
  uint16_t hi = __builtin_bit_cast(uint16_t, __float2bfloat16(b));
  return (uint32_t)lo | ((uint32_t)hi << 16);
}

// threefry2x32, key (0,42): ks = [0, 42, 0^42^0x1BD11BDA]; returns y0^y1
__device__ __forceinline__ uint32_t threefry_xor_0_42(uint32_t x0, uint32_t x1) {
  const uint32_t K1 = 42u;
  const uint32_t K2 = 0x1BD11BF0u;
  x1 += K1;
#define TFR(r) { x0 += x1; x1 = (x1 << (r)) | (x1 >> (32 - (r))); x1 ^= x0; }
  TFR(13) TFR(15) TFR(26) TFR(6)
  x0 += K1;  x1 += K2 + 1u;
  TFR(17) TFR(29) TFR(16) TFR(24)
  x0 += K2;  x1 += 2u;
  TFR(13) TFR(15) TFR(26) TFR(6)
             x1 += K1 + 3u;
  TFR(17) TFR(29) TFR(16) TFR(24)
  x0 += K1;  x1 += K2 + 4u;
  TFR(13) TFR(15) TFR(26) TFR(6)
  x0 += K2;  x1 += 5u;
#undef TFR
  return x0 ^ x1;
}

// LDS layout: flat arrays of 512 x 16B "entries" (4 u32 = 8 bf16 along K).
//  K  entry (Tk,kc,g,e) = ((Tk*2+kc)*4+g)*16+e : K[key=Tk*16+e][d=kc*32+8g..+7]
//  V  entry (dt,gk,e)   = (dt*8+gk)*16+e       : V[key=8gk..8gk+7][d=dt*16+e]
//  P  entry (w,gp,e)    = (w*8+gp)*16+e        : P[query=e][key=8gp..8gp+7]
// All fragment reads/writes are 64 consecutive entries per wave -> conflict-free.

__global__ __launch_bounds__(256, 4)
void attn_dropout_kernel(const float* __restrict__ Qg, const float* __restrict__ Kg,
                         const float* __restrict__ Vg, const float* __restrict__ invs,
                         float* __restrict__ Out) {
  __shared__ __align__(16) uint32_t KbF[512 * 4];
  __shared__ __align__(16) uint32_t VtF[512 * 4];
  __shared__ __align__(16) uint32_t PlF[512 * 4];

  const int tid = threadIdx.x;
  const int w = tid >> 6;
  const int l = tid & 63;
  const int e = l & 15;
  const int g = l >> 4;

  // block decode with XCD affinity: 4 (b,h) groups per XCD, 32 q-chunks each
  const int n  = blockIdx.x;                     // 0..1023
  const int bh = (n & 7) * 4 + ((n >> 3) & 3);   // 0..31
  const int b  = bh >> 4;
  const int h  = bh & 15;
  const int qc = n >> 5;                         // 0..31
  const int qbase = qc * 64;

  const float c = 1.4426950408889634f / invs[0]; // log2(e)/inv_scale (post-MFMA)
  const int sq = qbase + w * 16 + e;             // this lane's query row

  // Q fragments (B operand: n-line = query e, k = d = kc*32 + 8g + j)
  short8 qf[2];
#pragma unroll
  for (int kc = 0; kc < 2; ++kc) {
    const float* qp = Qg + (((b * 2048 + sq) * 16 + h) * 64 + kc * 32 + 8 * g);
    f32x4 q0 = *(const f32x4*)qp;
    f32x4 q1 = *(const f32x4*)(qp + 4);
    u32x4 u;
    u.x = pack2bf(q0.x, q0.y);
    u.y = pack2bf(q0.z, q0.w);
    u.z = pack2bf(q1.x, q1.y);
    u.w = pack2bf(q1.z, q1.w);
    qf[kc] = __builtin_bit_cast(short8, u);
  }

  f32x4 acc[4];
#pragma unroll
  for (int dt = 0; dt < 4; ++dt) acc[dt] = (f32x4){0.f, 0.f, 0.f, 0.f};
  float lsum = 0.f;

  // mask flat index: f = b*2^26 + h*2^22 + s*2^11 + t
  const uint32_t fb = ((uint32_t)b << 26) | ((uint32_t)h << 22) | ((uint32_t)sq << 11);

  // staging roles
  const int s_e = tid & 15, s_g = (tid >> 4) & 3, s_kc = (tid >> 6) & 1, s_T = tid >> 7;
  const int v_e = tid & 15, v_gk = (tid >> 4) & 7, v_dt = tid >> 7;

  for (int tile = 0; tile < 32; ++tile) {
    const int t0 = tile * 64;
    __syncthreads();   // prev tile's LDS reads done before overwrite
    // ---- stage K: one 16B entry per thread per r2 (linear b128 writes) ----
#pragma unroll
    for (int r2 = 0; r2 < 2; ++r2) {
      int Tk = s_T + 2 * r2;
      const float* p = Kg + (((b * 2048 + t0 + Tk * 16 + s_e) * 16 + h) * 64 + s_kc * 32 + 8 * s_g);
      f32x4 a0 = *(const f32x4*)p;
      f32x4 a1 = *(const f32x4*)(p + 4);
      u32x4 u;
      u.x = pack2bf(a0.x, a0.y);
      u.y = pack2bf(a0.z, a0.w);
      u.z = pack2bf(a1.x, a1.y);
      u.w = pack2bf(a1.z, a1.w);
      *(u32x4*)&KbF[(((Tk * 2 + s_kc) * 4 + s_g) * 16 + s_e) * 4] = u;
    }
    // ---- stage V transposed: 8 key-rows of one d column -> one entry ----
#pragma unroll
    for (int r2 = 0; r2 < 2; ++r2) {
      int dt = v_dt + 2 * r2;
      int d = dt * 16 + v_e;
      const float* p = Vg + (((b * 2048 + t0 + 8 * v_gk) * 16 + h) * 64 + d);
      float vv[8];
#pragma unroll
      for (int r = 0; r < 8; ++r) vv[r] = p[r * 1024];   // key stride = 16*64 floats
      u32x4 u;
      u.x = pack2bf(vv[0], vv[1]);
      u.y = pack2bf(vv[2], vv[3]);
      u.z = pack2bf(vv[4], vv[5]);
      u.w = pack2bf(vv[6], vv[7]);
      *(u32x4*)&VtF[((dt * 8 + v_gk) * 16 + v_e) * 4] = u;
    }
    __syncthreads();

    // ---- QK^T + softmax numerator + dropout mask ----
#pragma unroll
    for (int Tk = 0; Tk < 4; ++Tk) {
      u32x4 ku0 = *(const u32x4*)&KbF[(((Tk * 2 + 0) * 4 + g) * 16 + e) * 4];
      u32x4 ku1 = *(const u32x4*)&KbF[(((Tk * 2 + 1) * 4 + g) * 16 + e) * 4];
      f32x4 sacc = (f32x4){0.f, 0.f, 0.f, 0.f};
      sacc = __builtin_amdgcn_mfma_f32_16x16x32_bf16(__builtin_bit_cast(short8, ku0), qf[0], sacc, 0, 0, 0);
      sacc = __builtin_amdgcn_mfma_f32_16x16x32_bf16(__builtin_bit_cast(short8, ku1), qf[1], sacc, 0, 0, 0);
      float pm[4];
#pragma unroll
      for (int r = 0; r < 4; ++r) {
        uint32_t f = fb + (uint32_t)(t0 + Tk * 16 + 4 * g + r);
        uint32_t bits = threefry_xor_0_42(0u, f);
        float pv = __builtin_amdgcn_exp2f(sacc[r] * c);
        lsum += pv;                         // denominator is pre-dropout
        pm[r] = (bits < KEEP_TH) ? pv : 0.f;
      }
      // relay write (wave-private, destination fragment order)
      int gp = 2 * Tk + (g >> 1);
      u32x2 pw;
      pw.x = pack2bf(pm[0], pm[1]);
      pw.y = pack2bf(pm[2], pm[3]);
      *(u32x2*)&PlF[((w * 8 + gp) * 16 + e) * 4 + 2 * (g & 1)] = pw;
    }
    asm volatile("" ::: "memory");  // same-wave DS ops are in-order; just pin compiler order

    // ---- PV ----
#pragma unroll
    for (int kk = 0; kk < 2; ++kk) {
      u32x4 pu = *(const u32x4*)&PlF[((w * 8 + g + 4 * kk) * 16 + e) * 4];
      short8 pf = __builtin_bit_cast(short8, pu);
#pragma unroll
      for (int dt = 0; dt < 4; ++dt) {
        u32x4 vu = *(const u32x4*)&VtF[((dt * 8 + g + 4 * kk) * 16 + e) * 4];
        acc[dt] = __builtin_amdgcn_mfma_f32_16x16x32_bf16(pf, __builtin_bit_cast(short8, vu), acc[dt], 0, 0, 0);
      }
    }
  }

  // ---- epilogue: out = acc / (0.9 * L) ----
  float L = lsum;
  L += __shfl_xor(L, 16);
  L += __shfl_xor(L, 32);               // full row-sum for query e in all g-lanes
  float rinv = 1.0f / (0.9f * L);
  float rr[4];
#pragma unroll
  for (int r = 0; r < 4; ++r) rr[r] = __shfl(rinv, 4 * g + r);  // rinv of query row 4g+r
#pragma unroll
  for (int dt = 0; dt < 4; ++dt)
#pragma unroll
    for (int r = 0; r < 4; ++r) {
      int s = qbase + w * 16 + 4 * g + r;      // D row = (lane>>4)*4 + reg
      Out[(((b * 16 + h) * 2048 + s) * 64) + dt * 16 + e] = acc[dt][r] * rr[r];
    }
}

extern "C" void kernel_launch(void* const* d_in, const int* in_sizes, int n_in,
                              void* d_out, int out_size, void* d_ws, size_t ws_size,
                              hipStream_t stream) {
  const float* q  = (const float*)d_in[0];
  const float* k  = (const float*)d_in[1];
  const float* v  = (const float*)d_in[2];
  const float* sc = (const float*)d_in[3];
  float* out = (float*)d_out;
  (void)d_ws; (void)ws_size; (void)in_sizes; (void)n_in; (void)out_size;
  attn_dropout_kernel<<<dim3(1024), dim3(256), 0, stream>>>(q, k, v, sc, out);
}

// Round 5
// 295.747 us; speedup vs baseline: 1.6143x; 1.0217x over previous
//
#include <hip/hip_runtime.h>
#include <hip/hip_bf16.h>
#include <stdint.h>

// B=2, H=16, S=2048, D=64, dropout p=0.1, key = jax.random.key(42)
// JAX partitionable threefry: bits(f) = y0^y1, (y0,y1)=threefry2x32(key,(0,f))
typedef __attribute__((ext_vector_type(8))) short short8;
typedef __attribute__((ext_vector_type(4))) float f32x4;
typedef __attribute__((ext_vector_type(4))) uint32_t u32x4;
typedef __attribute__((ext_vector_type(2))) uint32_t u32x2;

#define KEEP_TH 0xE6666600u  // bits < TH  <=>  jax uniform(bits) < float32(0.9)

__device__ __forceinline__ uint32_t pack2bf(float a, float b) {
  uint16_t lo = __builtin_bit_cast(uint16_t, __float2bfloat16(a));
  uint16_t hi = __builtin_bit_cast(uint16_t, __float2bfloat16(b));
  return (uint32_t)lo | ((uint32_t)hi << 16);
}

// threefry2x32 with key (0,42), counter (0, f), x1pre = f + 42 already added.
// ks = [0, 42, 0x1BD11BF0]. Returns y0 ^ y1.
__device__ __forceinline__ uint32_t tf_bits(uint32_t x1pre) {
  uint32_t x1 = x1pre;
  uint32_t x0 = x1;                                   // round 1: x0 = 0 + x1
  x1 = __builtin_rotateleft32(x1, 13) ^ x0;
#define R(r) { x0 += x1; x1 = __builtin_rotateleft32(x1, (r)) ^ x0; }
  R(15) R(26) R(6)
  x0 += 42u;          x1 += 0x1BD11BF0u + 1u;
  R(17) R(29) R(16) R(24)
  x0 += 0x1BD11BF0u;  x1 += 2u;
  R(13) R(15) R(26) R(6)
                      x1 += 42u + 3u;
  R(17) R(29) R(16) R(24)
  x0 += 42u;          x1 += 0x1BD11BF0u + 4u;
  R(13) R(15) R(26) R(6)
  x0 += 0x1BD11BF0u;  x1 += 5u;
#undef R
  return x0 ^ x1;
}

// LDS layout: flat arrays of 512 x 16B "entries" (4 u32 = 8 bf16 along K).
//  K  entry (Tk,kc,g,e) = ((Tk*2+kc)*4+g)*16+e : K[key=Tk*16+e][d=kc*32+8g..+7]
//  V  entry (dt,gk,e)   = (dt*8+gk)*16+e       : V[key=8gk..8gk+7][d=dt*16+e]
//  P  entry (w,gp,e)    = (w*8+gp)*16+e        : P[query=e][key=8gp..8gp+7]
// All fragment reads/writes are 64 consecutive entries per wave -> conflict-free.

__global__ __launch_bounds__(256, 4)
void attn_dropout_kernel(const float* __restrict__ Qg, const float* __restrict__ Kg,
                         const float* __restrict__ Vg, const float* __restrict__ invs,
                         float* __restrict__ Out) {
  __shared__ __align__(16) uint32_t KbF[512 * 4];
  __shared__ __align__(16) uint32_t VtF[512 * 4];
  __shared__ __align__(16) uint32_t PlF[512 * 4];

  const int tid = threadIdx.x;
  const int w = tid >> 6;
  const int l = tid & 63;
  const int e = l & 15;
  const int g = l >> 4;

  // block decode with XCD affinity: 4 (b,h) groups per XCD, 32 q-chunks each
  const int n  = blockIdx.x;                     // 0..1023
  const int bh = (n & 7) * 4 + ((n >> 3) & 3);   // 0..31
  const int b  = bh >> 4;
  const int h  = bh & 15;
  const int qc = n >> 5;                         // 0..31
  const int qbase = qc * 64;

  const float c = 1.4426950408889634f / invs[0]; // log2(e)/inv_scale, folded into Q
  const int sq = qbase + w * 16 + e;             // this lane's query row

  // Q fragments (B operand: n-line = query e, k = d = kc*32 + 8g + j), pre-scaled by c
  short8 qf[2];
#pragma unroll
  for (int kc = 0; kc < 2; ++kc) {
    const float* qp = Qg + (((b * 2048 + sq) * 16 + h) * 64 + kc * 32 + 8 * g);
    f32x4 q0 = *(const f32x4*)qp;
    f32x4 q1 = *(const f32x4*)(qp + 4);
    u32x4 u;
    u.x = pack2bf(q0.x * c, q0.y * c);
    u.y = pack2bf(q0.z * c, q0.w * c);
    u.z = pack2bf(q1.x * c, q1.y * c);
    u.w = pack2bf(q1.z * c, q1.w * c);
    qf[kc] = __builtin_bit_cast(short8, u);
  }

  f32x4 acc[4];
#pragma unroll
  for (int dt = 0; dt < 4; ++dt) acc[dt] = (f32x4){0.f, 0.f, 0.f, 0.f};
  float lsum = 0.f;

  // mask flat index: f = b*2^26 + h*2^22 + s*2^11 + t
  const uint32_t fb = ((uint32_t)b << 26) | ((uint32_t)h << 22) | ((uint32_t)sq << 11);

  // staging roles
  const int s_e = tid & 15, s_g = (tid >> 4) & 3, s_kc = (tid >> 6) & 1, s_T = tid >> 7;
  const int v_e = tid & 15, v_gk = (tid >> 4) & 7, v_dt = tid >> 7;

  for (int tile = 0; tile < 32; ++tile) {
    const int t0 = tile * 64;
    __syncthreads();   // prev tile's LDS reads done before overwrite
    // ---- stage K: one 16B entry per thread per r2 (linear b128 writes) ----
#pragma unroll
    for (int r2 = 0; r2 < 2; ++r2) {
      int Tk = s_T + 2 * r2;
      const float* p = Kg + (((b * 2048 + t0 + Tk * 16 + s_e) * 16 + h) * 64 + s_kc * 32 + 8 * s_g);
      f32x4 a0 = *(const f32x4*)p;
      f32x4 a1 = *(const f32x4*)(p + 4);
      u32x4 u;
      u.x = pack2bf(a0.x, a0.y);
      u.y = pack2bf(a0.z, a0.w);
      u.z = pack2bf(a1.x, a1.y);
      u.w = pack2bf(a1.z, a1.w);
      *(u32x4*)&KbF[(((Tk * 2 + s_kc) * 4 + s_g) * 16 + s_e) * 4] = u;
    }
    // ---- stage V transposed: 8 key-rows of one d column -> one entry ----
#pragma unroll
    for (int r2 = 0; r2 < 2; ++r2) {
      int dt = v_dt + 2 * r2;
      int d = dt * 16 + v_e;
      const float* p = Vg + (((b * 2048 + t0 + 8 * v_gk) * 16 + h) * 64 + d);
      float vv[8];
#pragma unroll
      for (int r = 0; r < 8; ++r) vv[r] = p[r * 1024];   // key stride = 16*64 floats
      u32x4 u;
      u.x = pack2bf(vv[0], vv[1]);
      u.y = pack2bf(vv[2], vv[3]);
      u.z = pack2bf(vv[4], vv[5]);
      u.w = pack2bf(vv[6], vv[7]);
      *(u32x4*)&VtF[((dt * 8 + v_gk) * 16 + v_e) * 4] = u;
    }
    __syncthreads();

    // ---- QK^T + softmax numerator + dropout mask ----
#pragma unroll
    for (int Tk = 0; Tk < 4; ++Tk) {
      u32x4 ku0 = *(const u32x4*)&KbF[(((Tk * 2 + 0) * 4 + g) * 16 + e) * 4];
      u32x4 ku1 = *(const u32x4*)&KbF[(((Tk * 2 + 1) * 4 + g) * 16 + e) * 4];
      f32x4 sacc = (f32x4){0.f, 0.f, 0.f, 0.f};
      sacc = __builtin_amdgcn_mfma_f32_16x16x32_bf16(__builtin_bit_cast(short8, ku0), qf[0], sacc, 0, 0, 0);
      sacc = __builtin_amdgcn_mfma_f32_16x16x32_bf16(__builtin_bit_cast(short8, ku1), qf[1], sacc, 0, 0, 0);
      // x1pre for r=0 of this Tk: f + 42 = fb + t0 + 16*Tk + 4*g + 42
      const uint32_t jT = fb + (uint32_t)(t0 + 16 * Tk + 4 * g + 42);
      float pm[4];
#pragma unroll
      for (int r = 0; r < 4; ++r) {
        uint32_t bits = tf_bits(jT + (uint32_t)r);
        float pv = __builtin_amdgcn_exp2f(sacc[r]);
        lsum += pv;                         // denominator is pre-dropout
        pm[r] = (bits < KEEP_TH) ? pv : 0.f;
      }
      // relay write (wave-private, destination fragment order)
      int gp = 2 * Tk + (g >> 1);
      u32x2 pw;
      pw.x = pack2bf(pm[0], pm[1]);
      pw.y = pack2bf(pm[2], pm[3]);
      *(u32x2*)&PlF[((w * 8 + gp) * 16 + e) * 4 + 2 * (g & 1)] = pw;
    }
    asm volatile("" ::: "memory");  // same-wave DS ops are in-order; pin compiler order

    // ---- PV ----
#pragma unroll
    for (int kk = 0; kk < 2; ++kk) {
      u32x4 pu = *(const u32x4*)&PlF[((w * 8 + g + 4 * kk) * 16 + e) * 4];
      short8 pf = __builtin_bit_cast(short8, pu);
#pragma unroll
      for (int dt = 0; dt < 4; ++dt) {
        u32x4 vu = *(const u32x4*)&VtF[((dt * 8 + g + 4 * kk) * 16 + e) * 4];
        acc[dt] = __builtin_amdgcn_mfma_f32_16x16x32_bf16(pf, __builtin_bit_cast(short8, vu), acc[dt], 0, 0, 0);
      }
    }
  }

  // ---- epilogue: out = acc / (0.9 * L) ----
  float L = lsum;
  L += __shfl_xor(L, 16);
  L += __shfl_xor(L, 32);               // full row-sum for query e in all g-lanes
  float rinv = 1.0f / (0.9f * L);
  float rr[4];
#pragma unroll
  for (int r = 0; r < 4; ++r) rr[r] = __shfl(rinv, 4 * g + r);  // rinv of query row 4g+r
#pragma unroll
  for (int dt = 0; dt < 4; ++dt)
#pragma unroll
    for (int r = 0; r < 4; ++r) {
      int s = qbase + w * 16 + 4 * g + r;      // D row = (lane>>4)*4 + reg
      Out[(((b * 16 + h) * 2048 + s) * 64) + dt * 16 + e] = acc[dt][r] * rr[r];
    }
}

extern "C" void kernel_launch(void* const* d_in, const int* in_sizes, int n_in,
                              void* d_out, int out_size, void* d_ws, size_t ws_size,
                              hipStream_t stream) {
  const float* q  = (const float*)d_in[0];
  const float* k  = (const float*)d_in[1];
  const float* v  = (const float*)d_in[2];
  const float* sc = (const float*)d_in[3];
  float* out = (float*)d_out;
  (void)d_ws; (void)ws_size; (void)in_sizes; (void)n_in; (void)out_size;
  attn_dropout_kernel<<<dim3(1024), dim3(256), 0, stream>>>(q, k, v, sc, out);
}

// Round 6
// 280.826 us; speedup vs baseline: 1.7001x; 1.0531x over previous
//
#include <hip/hip_runtime.h>
#include <hip/hip_bf16.h>
#include <stdint.h>

// B=2, H=16, S=2048, D=64, dropout p=0.1, key = jax.random.key(42)
// JAX partitionable threefry: bits(f) = y0^y1, (y0,y1)=threefry2x32(key,(0,f))
typedef __attribute__((ext_vector_type(8))) short short8;
typedef __attribute__((ext_vector_type(4))) float f32x4;
typedef __attribute__((ext_vector_type(4))) uint32_t u32x4;
typedef __attribute__((ext_vector_type(2))) uint32_t u32x2;

#define KEEP_TH 0xE6666600u  // bits < TH  <=>  jax uniform(bits) < float32(0.9)

// 2× f32 -> packed bf16 pair in ONE op (RNE). No builtin on gfx950; inline asm.
__device__ __forceinline__ uint32_t pkbf(float lo, float hi) {
  uint32_t r;
  asm("v_cvt_pk_bf16_f32 %0, %1, %2" : "=v"(r) : "v"(lo), "v"(hi));
  return r;
}

// threefry2x32 with key (0,42), counter (0, f), x1pre = f + 42 already added.
// ks = [0, 42, 0x1BD11BF0]. Returns y0 ^ y1.
__device__ __forceinline__ uint32_t tf_bits(uint32_t x1pre) {
  uint32_t x1 = x1pre;
  uint32_t x0 = x1;                                   // round 1: x0 = 0 + x1
  x1 = __builtin_rotateleft32(x1, 13) ^ x0;
#define R(r) { x0 += x1; x1 = __builtin_rotateleft32(x1, (r)) ^ x0; }
  R(15) R(26) R(6)
  x0 += 42u;          x1 += 0x1BD11BF0u + 1u;
  R(17) R(29) R(16) R(24)
  x0 += 0x1BD11BF0u;  x1 += 2u;
  R(13) R(15) R(26) R(6)
                      x1 += 42u + 3u;
  R(17) R(29) R(16) R(24)
  x0 += 42u;          x1 += 0x1BD11BF0u + 4u;
  R(13) R(15) R(26) R(6)
  x0 += 0x1BD11BF0u;  x1 += 5u;
#undef R
  return x0 ^ x1;
}

// LDS layout: flat arrays of 512 x 16B "entries" (4 u32 = 8 bf16 along K).
//  K  entry (Tk,kc,g,e) = ((Tk*2+kc)*4+g)*16+e : K[key=Tk*16+e][d=kc*32+8g..+7]
//  V  entry (dt,gk,e)   = (dt*8+gk)*16+e       : V[key=8gk..8gk+7][d=dt*16+e]
//  P  entry (w,gp,e)    = (w*8+gp)*16+e        : P[query=e][key=8gp..8gp+7]
// All fragment reads/writes are 64 consecutive entries per wave -> conflict-free.

__global__ __launch_bounds__(256, 4)
void attn_dropout_kernel(const float* __restrict__ Qg, const float* __restrict__ Kg,
                         const float* __restrict__ Vg, const float* __restrict__ invs,
                         float* __restrict__ Out) {
  __shared__ __align__(16) uint32_t KbF[512 * 4];
  __shared__ __align__(16) uint32_t VtF[512 * 4];
  __shared__ __align__(16) uint32_t PlF[512 * 4];

  const int tid = threadIdx.x;
  const int w = tid >> 6;
  const int l = tid & 63;
  const int e = l & 15;
  const int g = l >> 4;

  // block decode with XCD affinity: 4 (b,h) groups per XCD, 32 q-chunks each
  const int n  = blockIdx.x;                     // 0..1023
  const int bh = (n & 7) * 4 + ((n >> 3) & 3);   // 0..31
  const int b  = bh >> 4;
  const int h  = bh & 15;
  const int qc = n >> 5;                         // 0..31
  const int qbase = qc * 64;

  const float c = 1.4426950408889634f / invs[0]; // log2(e)/inv_scale, folded into Q
  const int sq = qbase + w * 16 + e;             // this lane's query row

  // Q fragments (B operand: n-line = query e, k = d = kc*32 + 8g + j), pre-scaled by c
  short8 qf[2];
#pragma unroll
  for (int kc = 0; kc < 2; ++kc) {
    const float* qp = Qg + (((b * 2048 + sq) * 16 + h) * 64 + kc * 32 + 8 * g);
    f32x4 q0 = *(const f32x4*)qp;
    f32x4 q1 = *(const f32x4*)(qp + 4);
    u32x4 u;
    u.x = pkbf(q0.x * c, q0.y * c);
    u.y = pkbf(q0.z * c, q0.w * c);
    u.z = pkbf(q1.x * c, q1.y * c);
    u.w = pkbf(q1.z * c, q1.w * c);
    qf[kc] = __builtin_bit_cast(short8, u);
  }

  f32x4 acc[4];
#pragma unroll
  for (int dt = 0; dt < 4; ++dt) acc[dt] = (f32x4){0.f, 0.f, 0.f, 0.f};
  float ls[4] = {0.f, 0.f, 0.f, 0.f};

  // mask flat index: f = b*2^26 + h*2^22 + s*2^11 + t
  const uint32_t fb = ((uint32_t)b << 26) | ((uint32_t)h << 22) | ((uint32_t)sq << 11);

  // staging roles
  const int s_e = tid & 15, s_g = (tid >> 4) & 3, s_kc = (tid >> 6) & 1, s_T = tid >> 7;
  const int v_e = tid & 15, v_gk = (tid >> 4) & 7, v_dt = tid >> 7;

  const float* kbase = Kg + (((b * 2048 + s_T * 16 + s_e) * 16 + h) * 64 + s_kc * 32 + 8 * s_g);
  const float* vbase = Vg + (((b * 2048 + 8 * v_gk) * 16 + h) * 64 + v_dt * 16 + v_e);

  // prefetch registers for next tile (T14 async-stage split)
  f32x4 kA[2], kB[2];
  float vR[2][8];

  // ---- prefetch tile 0 ----
#pragma unroll
  for (int r2 = 0; r2 < 2; ++r2) {
    const float* p = kbase + r2 * (32 * 16 * 64);          // Tk += 2
    kA[r2] = *(const f32x4*)p;
    kB[r2] = *(const f32x4*)(p + 4);
    const float* pv = vbase + r2 * (2 * 16 * 64);          // dt += 2 -> d += 32
#pragma unroll
    for (int r = 0; r < 8; ++r) vR[r2][r] = pv[r * 1024 - r2 * (2 * 16 * 64) + r2 * 32];
  }
  // note: the vbase trick above must keep d-offset: rewrite plainly below in loop for clarity

  for (int tile = 0; tile < 32; ++tile) {
    const int t0 = tile * 64;
    __syncthreads();   // prev tile's LDS reads done before overwrite

    // ---- store prefetched tile into LDS (cvt_pk + linear b128/b64 writes) ----
#pragma unroll
    for (int r2 = 0; r2 < 2; ++r2) {
      int Tk = s_T + 2 * r2;
      u32x4 u;
      u.x = pkbf(kA[r2].x, kA[r2].y);
      u.y = pkbf(kA[r2].z, kA[r2].w);
      u.z = pkbf(kB[r2].x, kB[r2].y);
      u.w = pkbf(kB[r2].z, kB[r2].w);
      *(u32x4*)&KbF[(((Tk * 2 + s_kc) * 4 + s_g) * 16 + s_e) * 4] = u;

      int dt = v_dt + 2 * r2;
      u32x4 uv;
      uv.x = pkbf(vR[r2][0], vR[r2][1]);
      uv.y = pkbf(vR[r2][2], vR[r2][3]);
      uv.z = pkbf(vR[r2][4], vR[r2][5]);
      uv.w = pkbf(vR[r2][6], vR[r2][7]);
      *(u32x4*)&VtF[((dt * 8 + v_gk) * 16 + v_e) * 4] = uv;
    }
    __syncthreads();

    // ---- issue next tile's global loads (latency hides under compute below) ----
    if (tile + 1 < 32) {
      const int t1 = (tile + 1) * 64;
#pragma unroll
      for (int r2 = 0; r2 < 2; ++r2) {
        const float* p = kbase + (t1 + r2 * 32) * (16 * 64);
        kA[r2] = *(const f32x4*)p;
        kB[r2] = *(const f32x4*)(p + 4);
        const float* pv = vbase + (t1) * (16 * 64) + r2 * 32;
#pragma unroll
        for (int r = 0; r < 8; ++r) vR[r2][r] = pv[r * 1024];
      }
    }

    // ---- QK^T + softmax numerator + dropout mask ----
#pragma unroll
    for (int Tk = 0; Tk < 4; ++Tk) {
      u32x4 ku0 = *(const u32x4*)&KbF[(((Tk * 2 + 0) * 4 + g) * 16 + e) * 4];
      u32x4 ku1 = *(const u32x4*)&KbF[(((Tk * 2 + 1) * 4 + g) * 16 + e) * 4];
      f32x4 sacc = (f32x4){0.f, 0.f, 0.f, 0.f};
      sacc = __builtin_amdgcn_mfma_f32_16x16x32_bf16(__builtin_bit_cast(short8, ku0), qf[0], sacc, 0, 0, 0);
      sacc = __builtin_amdgcn_mfma_f32_16x16x32_bf16(__builtin_bit_cast(short8, ku1), qf[1], sacc, 0, 0, 0);
      // x1pre for r=0 of this Tk: f + 42 = fb + t0 + 16*Tk + 4*g + 42
      const uint32_t jT = fb + (uint32_t)(t0 + 16 * Tk + 4 * g + 42);
      float pm[4];
#pragma unroll
      for (int r = 0; r < 4; ++r) {
        uint32_t bits = tf_bits(jT + (uint32_t)r);
        float pv = __builtin_amdgcn_exp2f(sacc[r]);
        ls[r] += pv;                        // denominator is pre-dropout
        pm[r] = (bits < KEEP_TH) ? pv : 0.f;
      }
      // relay write (wave-private, destination fragment order)
      int gp = 2 * Tk + (g >> 1);
      u32x2 pw;
      pw.x = pkbf(pm[0], pm[1]);
      pw.y = pkbf(pm[2], pm[3]);
      *(u32x2*)&PlF[((w * 8 + gp) * 16 + e) * 4 + 2 * (g & 1)] = pw;
    }
    asm volatile("" ::: "memory");  // same-wave DS ops are in-order; pin compiler order

    // ---- PV ----
#pragma unroll
    for (int kk = 0; kk < 2; ++kk) {
      u32x4 pu = *(const u32x4*)&PlF[((w * 8 + g + 4 * kk) * 16 + e) * 4];
      short8 pf = __builtin_bit_cast(short8, pu);
#pragma unroll
      for (int dt = 0; dt < 4; ++dt) {
        u32x4 vu = *(const u32x4*)&VtF[((dt * 8 + g + 4 * kk) * 16 + e) * 4];
        acc[dt] = __builtin_amdgcn_mfma_f32_16x16x32_bf16(pf, __builtin_bit_cast(short8, vu), acc[dt], 0, 0, 0);
      }
    }
  }

  // ---- epilogue: out = acc / (0.9 * L) ----
  float L = (ls[0] + ls[1]) + (ls[2] + ls[3]);
  L += __shfl_xor(L, 16);
  L += __shfl_xor(L, 32);               // full row-sum for query e in all g-lanes
  float rinv = 1.0f / (0.9f * L);
  float rr[4];
#pragma unroll
  for (int r = 0; r < 4; ++r) rr[r] = __shfl(rinv, 4 * g + r);  // rinv of query row 4g+r
#pragma unroll
  for (int dt = 0; dt < 4; ++dt)
#pragma unroll
    for (int r = 0; r < 4; ++r) {
      int s = qbase + w * 16 + 4 * g + r;      // D row = (lane>>4)*4 + reg
      Out[(((b * 16 + h) * 2048 + s) * 64) + dt * 16 + e] = acc[dt][r] * rr[r];
    }
}

extern "C" void kernel_launch(void* const* d_in, const int* in_sizes, int n_in,
                              void* d_out, int out_size, void* d_ws, size_t ws_size,
                              hipStream_t stream) {
  const float* q  = (const float*)d_in[0];
  const float* k  = (const float*)d_in[1];
  const float* v  = (const float*)d_in[2];
  const float* sc = (const float*)d_in[3];
  float* out = (float*)d_out;
  (void)d_ws; (void)ws_size; (void)in_sizes; (void)n_in; (void)out_size;
  attn_dropout_kernel<<<dim3(1024), dim3(256), 0, stream>>>(q, k, v, sc, out);
}